// Round 10
// baseline (210.947 us; speedup 1.0000x reference)
//
#include <hip/hip_runtime.h>

// B=4, N=1024, E=1024, H=16, D=64.  bf16 MFMA (16x16x32), fp32 accum.
// Raw-reshape: per batch-head bh, Q/K/V slab = flat [bh*65536, +65536) viewed [1024 n][64 d].
// QKV GEMM writes q/k/v linearly; Q PRE-SCALED by 0.125*log2(e) -> exp2-domain softmax.
// transpose_v builds V^T per head. Attention: swapped QK^T (lane-local softmax), 4-wave
// split-K, causal pairing, XCD remap, defer-max (local check), diag-only masking.
// Round 10: TLP push — kf-reuse prefetch (no kn; VGPR down), launch_bounds(256,6),
// f16 l-normalized merge staging (LDS 35840->17920), vector lsum (zero per-tile shuffles).

typedef __bf16 bf16x8 __attribute__((ext_vector_type(8)));
typedef float f32x4 __attribute__((ext_vector_type(4)));

#define QSCALE 0.18033688011112042f   // 0.125 * log2(e)
#define DEFER_THR 11.0f               // log2 domain; P bounded by 2^11

__device__ __forceinline__ unsigned short f2bf(float f) {
    unsigned u = __float_as_uint(f);
    u += 0x7fffu + ((u >> 16) & 1u);   // round-to-nearest-even
    return (unsigned short)(u >> 16);
}

__device__ __forceinline__ unsigned cvtpk_bf16(float lo, float hi) {
    unsigned r;
    asm("v_cvt_pk_bf16_f32 %0, %1, %2" : "=v"(r) : "v"(lo), "v"(hi));
    return r;
}

union FragU { uint4 u; bf16x8 v; };

__device__ __forceinline__ bf16x8 ld_frag(const unsigned short* p) {
    FragU x; x.u = *(const uint4*)p; return x.v;
}

__device__ __forceinline__ void gload_lds16(const void* g, void* l) {
    __builtin_amdgcn_global_load_lds(
        (const __attribute__((address_space(1))) void*)g,
        (__attribute__((address_space(3))) void*)l, 16, 0, 0);
}

// ---------------- fp32 -> bf16 elementwise ----------------
__global__ void cvt_bf16(const float* __restrict__ in, unsigned short* __restrict__ out, int n4) {
    int i = blockIdx.x * blockDim.x + threadIdx.x;
    int stride = gridDim.x * blockDim.x;
    for (; i < n4; i += stride) {
        float4 f = ((const float4*)in)[i];
        unsigned a = (unsigned)f2bf(f.x) | ((unsigned)f2bf(f.y) << 16);
        unsigned b = (unsigned)f2bf(f.z) | ((unsigned)f2bf(f.w) << 16);
        ((uint2*)out)[i] = make_uint2(a, b);
    }
}

// ---------------- fp32 [rows][cols] -> bf16 [cols][rows] ----------------
__global__ void transpose_cvt(const float* __restrict__ W, unsigned short* __restrict__ Wt,
                              int rows, int cols) {
    __shared__ float tile[32][33];
    int c0 = blockIdx.x * 32, r0 = blockIdx.y * 32;
    for (int i = threadIdx.y; i < 32; i += 8)
        tile[i][threadIdx.x] = W[(r0 + i) * cols + c0 + threadIdx.x];
    __syncthreads();
    for (int i = threadIdx.y; i < 32; i += 8)
        Wt[(c0 + i) * (long)rows + r0 + threadIdx.x] = f2bf(tile[threadIdx.x][i]);
}

// ---------------- per-head V transpose: [1024 n][64 d] -> [64 d][1024 n] ----------------
__global__ void transpose_v(const unsigned short* __restrict__ v,
                            unsigned short* __restrict__ vt) {
    __shared__ unsigned short tile[32][33];
    int bh = blockIdx.z;
    int n0 = blockIdx.x * 32, d0 = blockIdx.y * 32;
    const unsigned short* src = v + (long)bh * 65536;
    unsigned short* dst = vt + (long)bh * 65536;
    for (int i = threadIdx.y; i < 32; i += 8)
        tile[i][threadIdx.x] = src[(n0 + i) * 64 + d0 + threadIdx.x];
    __syncthreads();
    for (int i = threadIdx.y; i < 32; i += 8)
        dst[(d0 + i) * 1024 + n0 + threadIdx.x] = tile[threadIdx.x][i];
}

// ---------------- bf16 GEMM, 128x128 tile, double-buffered global_load_lds ----------------
template <int MODE>
__global__ __launch_bounds__(256) void gemm128(
    const unsigned short* __restrict__ A,    // [M,1024] bf16
    const unsigned short* __restrict__ Bt,   // [N,1024] bf16
    const float* __restrict__ bias,          // [N]
    unsigned short* __restrict__ qb,
    unsigned short* __restrict__ kb,
    unsigned short* __restrict__ vb,
    float* __restrict__ outf)
{
    const int K = 1024;
    __shared__ unsigned short As[2][4096];   // [128][32] linear per buffer
    __shared__ unsigned short Bs[2][4096];
    int t = threadIdx.x, lane = t & 63, w = t >> 6;
    int wm = w >> 1, wn = w & 1;             // 2x2 waves, 64x64 per wave
    int lrow = lane >> 4, lcol = lane & 15;
    int tn0 = blockIdx.x * 128, tm0 = blockIdx.y * 128;

    int seg0 = w * 1024;
    int seg1 = (w + 4) * 1024;
    int off0 = seg0 + lane * 16, off1 = seg1 + lane * 16;
    int r0 = off0 >> 6, cb0 = off0 & 63;
    int r1 = off1 >> 6, cb1 = off1 & 63;

    const char* gA = (const char*)A;
    const char* gB = (const char*)Bt;

    f32x4 acc[4][4] = {};

    auto STAGE = [&](int buf, int kt) {
        long kby = (long)kt * 2;
        gload_lds16(gA + (long)(tm0 + r0) * 2048 + kby + cb0, (char*)&As[buf][0] + seg0);
        gload_lds16(gA + (long)(tm0 + r1) * 2048 + kby + cb1, (char*)&As[buf][0] + seg1);
        gload_lds16(gB + (long)(tn0 + r0) * 2048 + kby + cb0, (char*)&Bs[buf][0] + seg0);
        gload_lds16(gB + (long)(tn0 + r1) * 2048 + kby + cb1, (char*)&Bs[buf][0] + seg1);
    };

    STAGE(0, 0);
    asm volatile("s_waitcnt vmcnt(0)");
    __syncthreads();

    int cur = 0;
    for (int kt = 0; kt < K; kt += 32) {
        if (kt + 32 < K) STAGE(cur ^ 1, kt + 32);

        bf16x8 af[4], bfr[4];
        #pragma unroll
        for (int mi = 0; mi < 4; ++mi)
            af[mi] = ld_frag(&As[cur][0] + (wm * 64 + mi * 16 + lcol) * 32 + lrow * 8);
        #pragma unroll
        for (int ni = 0; ni < 4; ++ni)
            bfr[ni] = ld_frag(&Bs[cur][0] + (wn * 64 + ni * 16 + lcol) * 32 + lrow * 8);
        #pragma unroll
        for (int mi = 0; mi < 4; ++mi)
            #pragma unroll
            for (int ni = 0; ni < 4; ++ni)
                acc[mi][ni] = __builtin_amdgcn_mfma_f32_16x16x32_bf16(af[mi], bfr[ni], acc[mi][ni], 0, 0, 0);

        __syncthreads();
        cur ^= 1;
    }

    #pragma unroll
    for (int mi = 0; mi < 4; ++mi) {
        int gr0 = tm0 + wm * 64 + mi * 16 + lrow * 4;
        #pragma unroll
        for (int ni = 0; ni < 4; ++ni) {
            int gc = tn0 + wn * 64 + ni * 16 + lcol;
            float bv = bias[gc];
            if (MODE == 0) {
                int sec = gc >> 10, ei = gc & 1023;
                unsigned short* dst = sec == 0 ? qb : (sec == 1 ? kb : vb);
                if (sec == 0) {
                    #pragma unroll
                    for (int r = 0; r < 4; ++r)
                        dst[(long)(gr0 + r) * 1024 + ei] = f2bf((acc[mi][ni][r] + bv) * QSCALE);
                } else {
                    #pragma unroll
                    for (int r = 0; r < 4; ++r)
                        dst[(long)(gr0 + r) * 1024 + ei] = f2bf(acc[mi][ni][r] + bv);
                }
            } else {
                #pragma unroll
                for (int r = 0; r < 4; ++r)
                    outf[(long)(gr0 + r) * 1024 + gc] = acc[mi][ni][r] + bv;
            }
        }
    }
}

// ---------------- flash attention: swapped QK^T + split-K + pairing + XCD remap ----------------
// Per-pass merge uses l-NORMALIZED partials: A_w = acc_w/l_w (f16), m'_w = m_w + log2(l_w).
// O = sum_w 2^(m'_w - M) A_w / sum_w 2^(m'_w - M)  ==  old e*acc/e*l merge exactly.
__global__ __launch_bounds__(256, 6) void attn(
    const unsigned short* __restrict__ qbuf,
    const unsigned short* __restrict__ kbuf,
    const unsigned short* __restrict__ vtbuf,
    unsigned short* __restrict__ obuf)
{
    // smem (17,920 B), phase-aliased:
    //   loop phase : Ps [4][32][40] ushort (10,240 B)
    //   merge phase: accH [4][32][68] f16 (17,408 B) + mS [4][32] f32 (512 B)
    __shared__ char smem[17920] __attribute__((aligned(16)));
    unsigned short (*Ps)[32][40] = (unsigned short (*)[32][40])smem;
    _Float16* accH = (_Float16*)smem;                 // [4][32][68]
    float* mS = (float*)(smem + 17408);               // [4][32]

    // XCD remap: id%8 = XCD; all 16 j-blocks of a bh on one XCD -> slab L2-resident.
    int id = blockIdx.x;
    int xcd = id & 7, slot = id >> 3;
    int bh = xcd + 8 * (slot >> 4);
    int j = slot & 15;

    const unsigned short* Q  = qbuf + (long)bh * 65536;
    const unsigned short* Kp = kbuf + (long)bh * 65536;
    const unsigned short* VT = vtbuf + (long)bh * 65536;   // [64 d][1024 n]
    unsigned short* O = obuf + (long)bh * 65536;
    int t = threadIdx.x, lane = t & 63, w = t >> 6;
    int lrow = lane >> 4, lcol = lane & 15;
    const float NEG = -__builtin_inff();

    #pragma unroll
    for (int pass = 0; pass < 2; ++pass) {
        int qt = pass == 0 ? j : 31 - j;
        int qbase = qt * 32;
        int T = qt + 1;                                // number of 32-key tiles

        bf16x8 qf[2][2];
        #pragma unroll
        for (int qg = 0; qg < 2; ++qg)
            #pragma unroll
            for (int kc = 0; kc < 2; ++kc)
                qf[qg][kc] = ld_frag(Q + (long)(qbase + qg * 16 + lcol) * 64 + kc * 32 + lrow * 8);

        f32x4 acc[2][4] = {};
        float m_i[2] = {NEG, NEG};
        float lsum[2][2] = {{0.f, 0.f}, {0.f, 0.f}};   // lane-local partial l (no shuffles)

        if (w < T) {
            int kt = w * 32;
            bf16x8 kf[2][2];
            #pragma unroll
            for (int kg = 0; kg < 2; ++kg)
                #pragma unroll
                for (int kc = 0; kc < 2; ++kc)
                    kf[kg][kc] = ld_frag(Kp + (long)(kt + kg * 16 + lcol) * 64 + kc * 32 + lrow * 8);

            for (;;) {
                // --- S^T = K * Qs (S in log2 domain) ---
                f32x4 s[2][2] = {};
                __builtin_amdgcn_s_setprio(1);
                #pragma unroll
                for (int kg = 0; kg < 2; ++kg)
                    #pragma unroll
                    for (int kc = 0; kc < 2; ++kc) {
                        s[0][kg] = __builtin_amdgcn_mfma_f32_16x16x32_bf16(kf[kg][kc], qf[0][kc], s[0][kg], 0, 0, 0);
                        s[1][kg] = __builtin_amdgcn_mfma_f32_16x16x32_bf16(kf[kg][kc], qf[1][kc], s[1][kg], 0, 0, 0);
                    }
                __builtin_amdgcn_s_setprio(0);

                int ktn = kt + 128;
                bool more = ktn < T * 32;
                // next K tile straight into kf (regs free after QK issue) -> no kn array
                if (more) {
                    #pragma unroll
                    for (int kg = 0; kg < 2; ++kg)
                        #pragma unroll
                        for (int kc = 0; kc < 2; ++kc)
                            kf[kg][kc] = ld_frag(Kp + (long)(ktn + kg * 16 + lcol) * 64 + kc * 32 + lrow * 8);
                }
                bf16x8 vf[4];
                #pragma unroll
                for (int dg = 0; dg < 4; ++dg)
                    vf[dg] = ld_frag(VT + (long)(dg * 16 + lcol) * 1024 + kt + lrow * 8);

                // --- gather S, mask only on the diagonal tile ---
                float tv[2][8], lmax[2];
                bool diag = (kt == qbase);
                #pragma unroll
                for (int qg = 0; qg < 2; ++qg) {
                    #pragma unroll
                    for (int kg = 0; kg < 2; ++kg)
                        #pragma unroll
                        for (int r = 0; r < 4; ++r)
                            tv[qg][kg * 4 + r] = s[qg][kg][r];
                    if (diag) {
                        #pragma unroll
                        for (int kg = 0; kg < 2; ++kg)
                            #pragma unroll
                            for (int r = 0; r < 4; ++r)
                                if (kg * 16 + lrow * 4 + r > qg * 16 + lcol)
                                    tv[qg][kg * 4 + r] = NEG;
                    }
                    float a0 = fmaxf(tv[qg][0], tv[qg][1]), a1 = fmaxf(tv[qg][2], tv[qg][3]);
                    float a2 = fmaxf(tv[qg][4], tv[qg][5]), a3 = fmaxf(tv[qg][6], tv[qg][7]);
                    lmax[qg] = fmaxf(fmaxf(a0, a1), fmaxf(a2, a3));
                }

                // --- defer-max: local check; full reduce+rescale in rare branch ---
                bool ok = (lmax[0] <= m_i[0] + DEFER_THR) && (lmax[1] <= m_i[1] + DEFER_THR);
                if (!__all(ok)) {
                    #pragma unroll
                    for (int qg = 0; qg < 2; ++qg) {
                        float mx = fmaxf(lmax[qg], __shfl_xor(lmax[qg], 16));
                        mx = fmaxf(mx, __shfl_xor(mx, 32));
                        float mnew = fmaxf(m_i[qg], mx);
                        float alpha = exp2f(m_i[qg] - mnew);
                        m_i[qg] = mnew;
                        lsum[qg][0] *= alpha;
                        lsum[qg][1] *= alpha;
                        #pragma unroll
                        for (int dg = 0; dg < 4; ++dg)
                            #pragma unroll
                            for (int r = 0; r < 4; ++r)
                                acc[qg][dg][r] *= alpha;
                    }
                }

                // --- p = 2^(s-m), pack via cvt_pk; l accumulated lane-locally ---
                #pragma unroll
                for (int qg = 0; qg < 2; ++qg) {
                    float p[8];
                    #pragma unroll
                    for (int jj = 0; jj < 8; ++jj) p[jj] = exp2f(tv[qg][jj] - m_i[qg]);
                    lsum[qg][0] += (p[0] + p[1]) + (p[2] + p[3]);
                    lsum[qg][1] += (p[4] + p[5]) + (p[6] + p[7]);
                    unsigned u0 = cvtpk_bf16(p[0], p[1]);
                    unsigned u1 = cvtpk_bf16(p[2], p[3]);
                    unsigned u2 = cvtpk_bf16(p[4], p[5]);
                    unsigned u3 = cvtpk_bf16(p[6], p[7]);
                    *(uint2*)&Ps[w][qg * 16 + lcol][lrow * 4]      = make_uint2(u0, u1);
                    *(uint2*)&Ps[w][qg * 16 + lcol][16 + lrow * 4] = make_uint2(u2, u3);
                }

                // --- O^T += V^T * P ---
                bf16x8 pb[2];
                pb[0] = ld_frag(&Ps[w][lcol][lrow * 8]);
                pb[1] = ld_frag(&Ps[w][16 + lcol][lrow * 8]);
                __builtin_amdgcn_s_setprio(1);
                #pragma unroll
                for (int dg = 0; dg < 4; ++dg) {
                    acc[0][dg] = __builtin_amdgcn_mfma_f32_16x16x32_bf16(vf[dg], pb[0], acc[0][dg], 0, 0, 0);
                    acc[1][dg] = __builtin_amdgcn_mfma_f32_16x16x32_bf16(vf[dg], pb[1], acc[1][dg], 0, 0, 0);
                }
                __builtin_amdgcn_s_setprio(0);

                if (!more) break;
                kt = ktn;
            }
        }

        // --- merge 4 wave-partials through LDS (f16 l-normalized) ---
        __syncthreads();   // all Ps reads done; smem becomes merge buffers
        #pragma unroll
        for (int qg = 0; qg < 2; ++qg) {
            int q = qg * 16 + lcol;
            float lr = lsum[qg][0] + lsum[qg][1];
            lr += __shfl_xor(lr, 16);
            lr += __shfl_xor(lr, 32);          // full l for this q (uniform across lrow)
            float mprime, inv;
            if (lr > 0.f) { mprime = m_i[qg] + log2f(lr); inv = 1.f / lr; }
            else          { mprime = NEG; inv = 0.f; }
            if (lrow == 0) mS[w * 32 + q] = mprime;
            #pragma unroll
            for (int dg = 0; dg < 4; ++dg) {
                _Float16 a0 = (_Float16)(acc[qg][dg][0] * inv);
                _Float16 a1 = (_Float16)(acc[qg][dg][1] * inv);
                _Float16 a2 = (_Float16)(acc[qg][dg][2] * inv);
                _Float16 a3 = (_Float16)(acc[qg][dg][3] * inv);
                _Float16* dst = &accH[(w * 32 + q) * 68 + dg * 16 + lrow * 4];
                dst[0] = a0; dst[1] = a1; dst[2] = a2; dst[3] = a3;
            }
        }
        __syncthreads();

        {
            int qq = t >> 3, d0 = (t & 7) * 8;
            float m0 = mS[qq], m1 = mS[32 + qq], m2 = mS[64 + qq], m3 = mS[96 + qq];
            float M = fmaxf(fmaxf(m0, m1), fmaxf(m2, m3));
            float e0 = exp2f(m0 - M), e1 = exp2f(m1 - M), e2 = exp2f(m2 - M), e3 = exp2f(m3 - M);
            float inv = 1.f / (e0 + e1 + e2 + e3);
            const _Float16* a0 = &accH[qq * 68 + d0];
            const _Float16* a1 = &accH[(32 + qq) * 68 + d0];
            const _Float16* a2 = &accH[(64 + qq) * 68 + d0];
            const _Float16* a3 = &accH[(96 + qq) * 68 + d0];
            unsigned short h[8];
            #pragma unroll
            for (int jj = 0; jj < 8; ++jj)
                h[jj] = f2bf((e0 * (float)a0[jj] + e1 * (float)a1[jj] +
                              e2 * (float)a2[jj] + e3 * (float)a3[jj]) * inv);
            uint4 pk;
            pk.x = (unsigned)h[0] | ((unsigned)h[1] << 16);
            pk.y = (unsigned)h[2] | ((unsigned)h[3] << 16);
            pk.z = (unsigned)h[4] | ((unsigned)h[5] << 16);
            pk.w = (unsigned)h[6] | ((unsigned)h[7] << 16);
            *(uint4*)&O[(long)(qbase + qq) * 64 + d0] = pk;
        }
        __syncthreads();   // merge reads done before next pass overwrites smem
    }
}

extern "C" void kernel_launch(void* const* d_in, const int* in_sizes, int n_in,
                              void* d_out, int out_size, void* d_ws, size_t ws_size,
                              hipStream_t stream) {
    const float* x    = (const float*)d_in[0];
    const float* Wqkv = (const float*)d_in[1];
    const float* bqkv = (const float*)d_in[2];
    const float* Wfc  = (const float*)d_in[3];
    const float* bfc  = (const float*)d_in[4];
    float* out = (float*)d_out;

    unsigned short* ws    = (unsigned short*)d_ws;
    unsigned short* xb    = ws;                    // 4M elems; dead after gemm<0>
    unsigned short* wqkvT = xb + (4u << 20);       // 3M
    unsigned short* wfcT  = wqkvT + (3u << 20);    // 1M
    unsigned short* qb    = wfcT + (1u << 20);     // 4M
    unsigned short* kb    = qb + (4u << 20);       // 4M
    unsigned short* vb    = kb + (4u << 20);       // 4M; dead after transpose_v
    unsigned short* vbT   = xb;                    // reuse xb
    unsigned short* ob    = vb;                    // reuse vb
    // total ws: 40 MB

    cvt_bf16<<<dim3(2048), dim3(256), 0, stream>>>(x, xb, (4 << 20) / 4);
    transpose_cvt<<<dim3(3072 / 32, 1024 / 32), dim3(32, 8), 0, stream>>>(Wqkv, wqkvT, 1024, 3072);
    transpose_cvt<<<dim3(1024 / 32, 1024 / 32), dim3(32, 8), 0, stream>>>(Wfc, wfcT, 1024, 1024);

    gemm128<0><<<dim3(24, 32), dim3(256), 0, stream>>>(xb, wqkvT, bqkv, qb, kb, vb, nullptr);
    transpose_v<<<dim3(32, 2, 64), dim3(32, 8), 0, stream>>>(vb, vbT);
    attn<<<dim3(1024), dim3(256), 0, stream>>>(qb, kb, vbT, ob);
    gemm128<1><<<dim3(8, 32), dim3(256), 0, stream>>>(ob, wfcT, bfc, nullptr, nullptr, nullptr, out);
}

// Round 11
// 116.243 us; speedup vs baseline: 1.8147x; 1.8147x over previous
//
#include <hip/hip_runtime.h>

// B=4, N=1024, E=1024, H=16, D=64.  bf16 MFMA (16x16x32), fp32 accum.
// Raw-reshape: per batch-head bh, Q/K/V slab = flat [bh*65536, +65536) viewed [1024 n][64 d].
// QKV GEMM writes q/k/v linearly; Q PRE-SCALED by 0.125*log2(e) -> exp2-domain softmax.
// transpose_v builds V^T per head. Attention: swapped QK^T (lane-local softmax), 4-wave
// split-K, causal pairing, XCD remap, defer-max (local check), diag-only masking,
// f16 l-normalized merge (LDS 17920), lane-local lsum, kf-reuse prefetch.
// Round 11: revert launch_bounds(256,6) [r10: forced VGPR 100->40, spilled, FETCH 12->247MB,
// 3x slower]; fuse prep kernels (8->6 dispatches); bijective XCD swizzle on GEMMs.

typedef __bf16 bf16x8 __attribute__((ext_vector_type(8)));
typedef float f32x4 __attribute__((ext_vector_type(4)));

#define QSCALE 0.18033688011112042f   // 0.125 * log2(e)
#define DEFER_THR 11.0f               // log2 domain; P bounded by 2^11

__device__ __forceinline__ unsigned short f2bf(float f) {
    unsigned u = __float_as_uint(f);
    u += 0x7fffu + ((u >> 16) & 1u);   // round-to-nearest-even
    return (unsigned short)(u >> 16);
}

__device__ __forceinline__ unsigned cvtpk_bf16(float lo, float hi) {
    unsigned r;
    asm("v_cvt_pk_bf16_f32 %0, %1, %2" : "=v"(r) : "v"(lo), "v"(hi));
    return r;
}

union FragU { uint4 u; bf16x8 v; };

__device__ __forceinline__ bf16x8 ld_frag(const unsigned short* p) {
    FragU x; x.u = *(const uint4*)p; return x.v;
}

__device__ __forceinline__ void gload_lds16(const void* g, void* l) {
    __builtin_amdgcn_global_load_lds(
        (const __attribute__((address_space(1))) void*)g,
        (__attribute__((address_space(3))) void*)l, 16, 0, 0);
}

// ---------------- fused prep: x->bf16 + both weight transposes (one launch) ----------------
// blocks [0,3072): Wqkv 32x32 transpose tiles; [3072,4096): Wfc tiles; [4096,5120): cvt x.
__global__ __launch_bounds__(256) void prep(
    const float* __restrict__ x,    unsigned short* __restrict__ xb,
    const float* __restrict__ Wqkv, unsigned short* __restrict__ wqkvT,
    const float* __restrict__ Wfc,  unsigned short* __restrict__ wfcT)
{
    __shared__ float tile[32][33];
    int bid = blockIdx.x;
    int tx = threadIdx.x & 31, ty = threadIdx.x >> 5;   // (32,8)
    if (bid < 3072) {
        int c0 = (bid % 96) * 32, r0 = (bid / 96) * 32;
        for (int i = ty; i < 32; i += 8)
            tile[i][tx] = Wqkv[(r0 + i) * 3072 + c0 + tx];
        __syncthreads();
        for (int i = ty; i < 32; i += 8)
            wqkvT[(long)(c0 + i) * 1024 + r0 + tx] = f2bf(tile[tx][i]);
    } else if (bid < 4096) {
        int b2 = bid - 3072;
        int c0 = (b2 % 32) * 32, r0 = (b2 / 32) * 32;
        for (int i = ty; i < 32; i += 8)
            tile[i][tx] = Wfc[(r0 + i) * 1024 + c0 + tx];
        __syncthreads();
        for (int i = ty; i < 32; i += 8)
            wfcT[(long)(c0 + i) * 1024 + r0 + tx] = f2bf(tile[tx][i]);
    } else {
        const int n4 = 1 << 20;                          // 4M floats as float4
        for (int i = (bid - 4096) * 256 + threadIdx.x; i < n4; i += 1024 * 256) {
            float4 f = ((const float4*)x)[i];
            unsigned a = (unsigned)f2bf(f.x) | ((unsigned)f2bf(f.y) << 16);
            unsigned b = (unsigned)f2bf(f.z) | ((unsigned)f2bf(f.w) << 16);
            ((uint2*)xb)[i] = make_uint2(a, b);
        }
    }
}

// ---------------- per-head V transpose: [1024 n][64 d] -> [64 d][1024 n] ----------------
__global__ void transpose_v(const unsigned short* __restrict__ v,
                            unsigned short* __restrict__ vt) {
    __shared__ unsigned short tile[32][33];
    int bh = blockIdx.z;
    int n0 = blockIdx.x * 32, d0 = blockIdx.y * 32;
    const unsigned short* src = v + (long)bh * 65536;
    unsigned short* dst = vt + (long)bh * 65536;
    for (int i = threadIdx.y; i < 32; i += 8)
        tile[i][threadIdx.x] = src[(n0 + i) * 64 + d0 + threadIdx.x];
    __syncthreads();
    for (int i = threadIdx.y; i < 32; i += 8)
        dst[(d0 + i) * 1024 + n0 + threadIdx.x] = tile[threadIdx.x][i];
}

// ---------------- bf16 GEMM, 128x128 tile, double-buffered global_load_lds ----------------
// 1D grid + bijective XCD swizzle: XCD gets a contiguous chunk -> A-panel L2 reuse.
template <int MODE>
__global__ __launch_bounds__(256) void gemm128(
    const unsigned short* __restrict__ A,    // [M,1024] bf16
    const unsigned short* __restrict__ Bt,   // [N,1024] bf16
    const float* __restrict__ bias,          // [N]
    unsigned short* __restrict__ qb,
    unsigned short* __restrict__ kb,
    unsigned short* __restrict__ vb,
    float* __restrict__ outf)
{
    const int K = 1024;
    __shared__ unsigned short As[2][4096];   // [128][32] linear per buffer
    __shared__ unsigned short Bs[2][4096];
    int t = threadIdx.x, lane = t & 63, w = t >> 6;
    int wm = w >> 1, wn = w & 1;             // 2x2 waves, 64x64 per wave
    int lrow = lane >> 4, lcol = lane & 15;

    const int NX  = (MODE == 0) ? 24 : 8;    // N-tiles
    const int CPX = (MODE == 0) ? 96 : 32;   // blocks per XCD chunk (grid/8)
    int id = blockIdx.x;
    int idp = (id & 7) * CPX + (id >> 3);    // bijective (grid % 8 == 0)
    int tn0 = (idp % NX) * 128, tm0 = (idp / NX) * 128;

    int seg0 = w * 1024;
    int seg1 = (w + 4) * 1024;
    int off0 = seg0 + lane * 16, off1 = seg1 + lane * 16;
    int r0 = off0 >> 6, cb0 = off0 & 63;
    int r1 = off1 >> 6, cb1 = off1 & 63;

    const char* gA = (const char*)A;
    const char* gB = (const char*)Bt;

    f32x4 acc[4][4] = {};

    auto STAGE = [&](int buf, int kt) {
        long kby = (long)kt * 2;
        gload_lds16(gA + (long)(tm0 + r0) * 2048 + kby + cb0, (char*)&As[buf][0] + seg0);
        gload_lds16(gA + (long)(tm0 + r1) * 2048 + kby + cb1, (char*)&As[buf][0] + seg1);
        gload_lds16(gB + (long)(tn0 + r0) * 2048 + kby + cb0, (char*)&Bs[buf][0] + seg0);
        gload_lds16(gB + (long)(tn0 + r1) * 2048 + kby + cb1, (char*)&Bs[buf][0] + seg1);
    };

    STAGE(0, 0);
    asm volatile("s_waitcnt vmcnt(0)");
    __syncthreads();

    int cur = 0;
    for (int kt = 0; kt < K; kt += 32) {
        if (kt + 32 < K) STAGE(cur ^ 1, kt + 32);

        bf16x8 af[4], bfr[4];
        #pragma unroll
        for (int mi = 0; mi < 4; ++mi)
            af[mi] = ld_frag(&As[cur][0] + (wm * 64 + mi * 16 + lcol) * 32 + lrow * 8);
        #pragma unroll
        for (int ni = 0; ni < 4; ++ni)
            bfr[ni] = ld_frag(&Bs[cur][0] + (wn * 64 + ni * 16 + lcol) * 32 + lrow * 8);
        #pragma unroll
        for (int mi = 0; mi < 4; ++mi)
            #pragma unroll
            for (int ni = 0; ni < 4; ++ni)
                acc[mi][ni] = __builtin_amdgcn_mfma_f32_16x16x32_bf16(af[mi], bfr[ni], acc[mi][ni], 0, 0, 0);

        __syncthreads();
        cur ^= 1;
    }

    #pragma unroll
    for (int mi = 0; mi < 4; ++mi) {
        int gr0 = tm0 + wm * 64 + mi * 16 + lrow * 4;
        #pragma unroll
        for (int ni = 0; ni < 4; ++ni) {
            int gc = tn0 + wn * 64 + ni * 16 + lcol;
            float bv = bias[gc];
            if (MODE == 0) {
                int sec = gc >> 10, ei = gc & 1023;
                unsigned short* dst = sec == 0 ? qb : (sec == 1 ? kb : vb);
                if (sec == 0) {
                    #pragma unroll
                    for (int r = 0; r < 4; ++r)
                        dst[(long)(gr0 + r) * 1024 + ei] = f2bf((acc[mi][ni][r] + bv) * QSCALE);
                } else {
                    #pragma unroll
                    for (int r = 0; r < 4; ++r)
                        dst[(long)(gr0 + r) * 1024 + ei] = f2bf(acc[mi][ni][r] + bv);
                }
            } else {
                #pragma unroll
                for (int r = 0; r < 4; ++r)
                    outf[(long)(gr0 + r) * 1024 + gc] = acc[mi][ni][r] + bv;
            }
        }
    }
}

// ---------------- flash attention: swapped QK^T + split-K + pairing + XCD remap ----------------
// Merge uses l-NORMALIZED partials: A_w = acc_w/l_w (f16), m'_w = m_w + log2(l_w).
__global__ __launch_bounds__(256) void attn(
    const unsigned short* __restrict__ qbuf,
    const unsigned short* __restrict__ kbuf,
    const unsigned short* __restrict__ vtbuf,
    unsigned short* __restrict__ obuf)
{
    // smem (17,920 B), phase-aliased:
    //   loop phase : Ps [4][32][40] ushort (10,240 B)
    //   merge phase: accH [4][32][68] f16 (17,408 B) + mS [4][32] f32 (512 B)
    __shared__ char smem[17920] __attribute__((aligned(16)));
    unsigned short (*Ps)[32][40] = (unsigned short (*)[32][40])smem;
    _Float16* accH = (_Float16*)smem;                 // [4][32][68]
    float* mS = (float*)(smem + 17408);               // [4][32]

    // XCD remap: id%8 = XCD; all 16 j-blocks of a bh on one XCD -> slab L2-resident.
    int id = blockIdx.x;
    int xcd = id & 7, slot = id >> 3;
    int bh = xcd + 8 * (slot >> 4);
    int j = slot & 15;

    const unsigned short* Q  = qbuf + (long)bh * 65536;
    const unsigned short* Kp = kbuf + (long)bh * 65536;
    const unsigned short* VT = vtbuf + (long)bh * 65536;   // [64 d][1024 n]
    unsigned short* O = obuf + (long)bh * 65536;
    int t = threadIdx.x, lane = t & 63, w = t >> 6;
    int lrow = lane >> 4, lcol = lane & 15;
    const float NEG = -__builtin_inff();

    #pragma unroll
    for (int pass = 0; pass < 2; ++pass) {
        int qt = pass == 0 ? j : 31 - j;
        int qbase = qt * 32;
        int T = qt + 1;                                // number of 32-key tiles

        bf16x8 qf[2][2];
        #pragma unroll
        for (int qg = 0; qg < 2; ++qg)
            #pragma unroll
            for (int kc = 0; kc < 2; ++kc)
                qf[qg][kc] = ld_frag(Q + (long)(qbase + qg * 16 + lcol) * 64 + kc * 32 + lrow * 8);

        f32x4 acc[2][4] = {};
        float m_i[2] = {NEG, NEG};
        float lsum[2][2] = {{0.f, 0.f}, {0.f, 0.f}};   // lane-local partial l

        if (w < T) {
            int kt = w * 32;
            bf16x8 kf[2][2];
            #pragma unroll
            for (int kg = 0; kg < 2; ++kg)
                #pragma unroll
                for (int kc = 0; kc < 2; ++kc)
                    kf[kg][kc] = ld_frag(Kp + (long)(kt + kg * 16 + lcol) * 64 + kc * 32 + lrow * 8);

            for (;;) {
                // --- S^T = K * Qs (S in log2 domain) ---
                f32x4 s[2][2] = {};
                __builtin_amdgcn_s_setprio(1);
                #pragma unroll
                for (int kg = 0; kg < 2; ++kg)
                    #pragma unroll
                    for (int kc = 0; kc < 2; ++kc) {
                        s[0][kg] = __builtin_amdgcn_mfma_f32_16x16x32_bf16(kf[kg][kc], qf[0][kc], s[0][kg], 0, 0, 0);
                        s[1][kg] = __builtin_amdgcn_mfma_f32_16x16x32_bf16(kf[kg][kc], qf[1][kc], s[1][kg], 0, 0, 0);
                    }
                __builtin_amdgcn_s_setprio(0);

                int ktn = kt + 128;
                bool more = ktn < T * 32;
                // next K tile straight into kf (regs free after QK issue)
                if (more) {
                    #pragma unroll
                    for (int kg = 0; kg < 2; ++kg)
                        #pragma unroll
                        for (int kc = 0; kc < 2; ++kc)
                            kf[kg][kc] = ld_frag(Kp + (long)(ktn + kg * 16 + lcol) * 64 + kc * 32 + lrow * 8);
                }
                bf16x8 vf[4];
                #pragma unroll
                for (int dg = 0; dg < 4; ++dg)
                    vf[dg] = ld_frag(VT + (long)(dg * 16 + lcol) * 1024 + kt + lrow * 8);

                // --- gather S, mask only on the diagonal tile ---
                float tv[2][8], lmax[2];
                bool diag = (kt == qbase);
                #pragma unroll
                for (int qg = 0; qg < 2; ++qg) {
                    #pragma unroll
                    for (int kg = 0; kg < 2; ++kg)
                        #pragma unroll
                        for (int r = 0; r < 4; ++r)
                            tv[qg][kg * 4 + r] = s[qg][kg][r];
                    if (diag) {
                        #pragma unroll
                        for (int kg = 0; kg < 2; ++kg)
                            #pragma unroll
                            for (int r = 0; r < 4; ++r)
                                if (kg * 16 + lrow * 4 + r > qg * 16 + lcol)
                                    tv[qg][kg * 4 + r] = NEG;
                    }
                    float a0 = fmaxf(tv[qg][0], tv[qg][1]), a1 = fmaxf(tv[qg][2], tv[qg][3]);
                    float a2 = fmaxf(tv[qg][4], tv[qg][5]), a3 = fmaxf(tv[qg][6], tv[qg][7]);
                    lmax[qg] = fmaxf(fmaxf(a0, a1), fmaxf(a2, a3));
                }

                // --- defer-max: local check; full reduce+rescale in rare branch ---
                bool ok = (lmax[0] <= m_i[0] + DEFER_THR) && (lmax[1] <= m_i[1] + DEFER_THR);
                if (!__all(ok)) {
                    #pragma unroll
                    for (int qg = 0; qg < 2; ++qg) {
                        float mx = fmaxf(lmax[qg], __shfl_xor(lmax[qg], 16));
                        mx = fmaxf(mx, __shfl_xor(mx, 32));
                        float mnew = fmaxf(m_i[qg], mx);
                        float alpha = exp2f(m_i[qg] - mnew);
                        m_i[qg] = mnew;
                        lsum[qg][0] *= alpha;
                        lsum[qg][1] *= alpha;
                        #pragma unroll
                        for (int dg = 0; dg < 4; ++dg)
                            #pragma unroll
                            for (int r = 0; r < 4; ++r)
                                acc[qg][dg][r] *= alpha;
                    }
                }

                // --- p = 2^(s-m), pack via cvt_pk; l accumulated lane-locally ---
                #pragma unroll
                for (int qg = 0; qg < 2; ++qg) {
                    float p[8];
                    #pragma unroll
                    for (int jj = 0; jj < 8; ++jj) p[jj] = exp2f(tv[qg][jj] - m_i[qg]);
                    lsum[qg][0] += (p[0] + p[1]) + (p[2] + p[3]);
                    lsum[qg][1] += (p[4] + p[5]) + (p[6] + p[7]);
                    unsigned u0 = cvtpk_bf16(p[0], p[1]);
                    unsigned u1 = cvtpk_bf16(p[2], p[3]);
                    unsigned u2 = cvtpk_bf16(p[4], p[5]);
                    unsigned u3 = cvtpk_bf16(p[6], p[7]);
                    *(uint2*)&Ps[w][qg * 16 + lcol][lrow * 4]      = make_uint2(u0, u1);
                    *(uint2*)&Ps[w][qg * 16 + lcol][16 + lrow * 4] = make_uint2(u2, u3);
                }

                // --- O^T += V^T * P ---
                bf16x8 pb[2];
                pb[0] = ld_frag(&Ps[w][lcol][lrow * 8]);
                pb[1] = ld_frag(&Ps[w][16 + lcol][lrow * 8]);
                __builtin_amdgcn_s_setprio(1);
                #pragma unroll
                for (int dg = 0; dg < 4; ++dg) {
                    acc[0][dg] = __builtin_amdgcn_mfma_f32_16x16x32_bf16(vf[dg], pb[0], acc[0][dg], 0, 0, 0);
                    acc[1][dg] = __builtin_amdgcn_mfma_f32_16x16x32_bf16(vf[dg], pb[1], acc[1][dg], 0, 0, 0);
                }
                __builtin_amdgcn_s_setprio(0);

                if (!more) break;
                kt = ktn;
            }
        }

        // --- merge 4 wave-partials through LDS (f16 l-normalized) ---
        __syncthreads();   // all Ps reads done; smem becomes merge buffers
        #pragma unroll
        for (int qg = 0; qg < 2; ++qg) {
            int q = qg * 16 + lcol;
            float lr = lsum[qg][0] + lsum[qg][1];
            lr += __shfl_xor(lr, 16);
            lr += __shfl_xor(lr, 32);          // full l for this q
            float mprime, inv;
            if (lr > 0.f) { mprime = m_i[qg] + log2f(lr); inv = 1.f / lr; }
            else          { mprime = NEG; inv = 0.f; }
            if (lrow == 0) mS[w * 32 + q] = mprime;
            #pragma unroll
            for (int dg = 0; dg < 4; ++dg) {
                _Float16 a0 = (_Float16)(acc[qg][dg][0] * inv);
                _Float16 a1 = (_Float16)(acc[qg][dg][1] * inv);
                _Float16 a2 = (_Float16)(acc[qg][dg][2] * inv);
                _Float16 a3 = (_Float16)(acc[qg][dg][3] * inv);
                _Float16* dst = &accH[(w * 32 + q) * 68 + dg * 16 + lrow * 4];
                dst[0] = a0; dst[1] = a1; dst[2] = a2; dst[3] = a3;
            }
        }
        __syncthreads();

        {
            int qq = t >> 3, d0 = (t & 7) * 8;
            float m0 = mS[qq], m1 = mS[32 + qq], m2 = mS[64 + qq], m3 = mS[96 + qq];
            float M = fmaxf(fmaxf(m0, m1), fmaxf(m2, m3));
            float e0 = exp2f(m0 - M), e1 = exp2f(m1 - M), e2 = exp2f(m2 - M), e3 = exp2f(m3 - M);
            float inv = 1.f / (e0 + e1 + e2 + e3);
            const _Float16* a0 = &accH[qq * 68 + d0];
            const _Float16* a1 = &accH[(32 + qq) * 68 + d0];
            const _Float16* a2 = &accH[(64 + qq) * 68 + d0];
            const _Float16* a3 = &accH[(96 + qq) * 68 + d0];
            unsigned short h[8];
            #pragma unroll
            for (int jj = 0; jj < 8; ++jj)
                h[jj] = f2bf((e0 * (float)a0[jj] + e1 * (float)a1[jj] +
                              e2 * (float)a2[jj] + e3 * (float)a3[jj]) * inv);
            uint4 pk;
            pk.x = (unsigned)h[0] | ((unsigned)h[1] << 16);
            pk.y = (unsigned)h[2] | ((unsigned)h[3] << 16);
            pk.z = (unsigned)h[4] | ((unsigned)h[5] << 16);
            pk.w = (unsigned)h[6] | ((unsigned)h[7] << 16);
            *(uint4*)&O[(long)(qbase + qq) * 64 + d0] = pk;
        }
        __syncthreads();   // merge reads done before next pass overwrites smem
    }
}

extern "C" void kernel_launch(void* const* d_in, const int* in_sizes, int n_in,
                              void* d_out, int out_size, void* d_ws, size_t ws_size,
                              hipStream_t stream) {
    const float* x    = (const float*)d_in[0];
    const float* Wqkv = (const float*)d_in[1];
    const float* bqkv = (const float*)d_in[2];
    const float* Wfc  = (const float*)d_in[3];
    const float* bfc  = (const float*)d_in[4];
    float* out = (float*)d_out;

    unsigned short* ws    = (unsigned short*)d_ws;
    unsigned short* xb    = ws;                    // 4M elems; dead after gemm<0>
    unsigned short* wqkvT = xb + (4u << 20);       // 3M
    unsigned short* wfcT  = wqkvT + (3u << 20);    // 1M
    unsigned short* qb    = wfcT + (1u << 20);     // 4M
    unsigned short* kb    = qb + (4u << 20);       // 4M
    unsigned short* vb    = kb + (4u << 20);       // 4M; dead after transpose_v
    unsigned short* vbT   = xb;                    // reuse xb
    unsigned short* ob    = vb;                    // reuse vb
    // total ws: 40 MB

    prep<<<dim3(5120), dim3(256), 0, stream>>>(x, xb, Wqkv, wqkvT, Wfc, wfcT);
    gemm128<0><<<dim3(768), dim3(256), 0, stream>>>(xb, wqkvT, bqkv, qb, kb, vb, nullptr);
    transpose_v<<<dim3(32, 2, 64), dim3(32, 8), 0, stream>>>(vb, vbT);
    attn<<<dim3(1024), dim3(256), 0, stream>>>(qb, kb, vbT, ob);
    gemm128<1><<<dim3(256), dim3(256), 0, stream>>>(ob, wfcT, bfc, nullptr, nullptr, nullptr, out);
}

// Round 12
// 115.812 us; speedup vs baseline: 1.8215x; 1.0037x over previous
//
#include <hip/hip_runtime.h>

// B=4, N=1024, E=1024, H=16, D=64.  bf16 MFMA (16x16x32), fp32 accum.
// Raw-reshape: per batch-head bh, Q/K/V slab = flat [bh*65536, +65536) viewed [1024 n][64 d].
// QKV GEMM writes q/k/v linearly; Q PRE-SCALED by 0.125*log2(e) -> exp2-domain softmax.
// transpose_v builds V^T per head. Attention: swapped QK^T (lane-local softmax), 4-wave
// split-K, causal pairing, XCD remap, defer-max (local check), diag-only masking,
// f16 l-normalized merge, lane-local lsum.
// Round 12: 2-stage ILP pipeline in attn — S(t) computed one iteration ahead; softmax(t)
// runs while QK(t+1) + PV(t) fill the MFMA pipe. tv[] scratch deleted (mask in-place on s)
// to keep VGPR <= ~120 (4 waves/SIMD).

typedef __bf16 bf16x8 __attribute__((ext_vector_type(8)));
typedef float f32x4 __attribute__((ext_vector_type(4)));

#define QSCALE 0.18033688011112042f   // 0.125 * log2(e)
#define DEFER_THR 11.0f               // log2 domain; P bounded by 2^11

__device__ __forceinline__ unsigned short f2bf(float f) {
    unsigned u = __float_as_uint(f);
    u += 0x7fffu + ((u >> 16) & 1u);   // round-to-nearest-even
    return (unsigned short)(u >> 16);
}

__device__ __forceinline__ unsigned cvtpk_bf16(float lo, float hi) {
    unsigned r;
    asm("v_cvt_pk_bf16_f32 %0, %1, %2" : "=v"(r) : "v"(lo), "v"(hi));
    return r;
}

union FragU { uint4 u; bf16x8 v; };

__device__ __forceinline__ bf16x8 ld_frag(const unsigned short* p) {
    FragU x; x.u = *(const uint4*)p; return x.v;
}

__device__ __forceinline__ void gload_lds16(const void* g, void* l) {
    __builtin_amdgcn_global_load_lds(
        (const __attribute__((address_space(1))) void*)g,
        (__attribute__((address_space(3))) void*)l, 16, 0, 0);
}

// ---------------- fused prep: x->bf16 + both weight transposes (one launch) ----------------
__global__ __launch_bounds__(256) void prep(
    const float* __restrict__ x,    unsigned short* __restrict__ xb,
    const float* __restrict__ Wqkv, unsigned short* __restrict__ wqkvT,
    const float* __restrict__ Wfc,  unsigned short* __restrict__ wfcT)
{
    __shared__ float tile[32][33];
    int bid = blockIdx.x;
    int tx = threadIdx.x & 31, ty = threadIdx.x >> 5;   // (32,8)
    if (bid < 3072) {
        int c0 = (bid % 96) * 32, r0 = (bid / 96) * 32;
        for (int i = ty; i < 32; i += 8)
            tile[i][tx] = Wqkv[(r0 + i) * 3072 + c0 + tx];
        __syncthreads();
        for (int i = ty; i < 32; i += 8)
            wqkvT[(long)(c0 + i) * 1024 + r0 + tx] = f2bf(tile[tx][i]);
    } else if (bid < 4096) {
        int b2 = bid - 3072;
        int c0 = (b2 % 32) * 32, r0 = (b2 / 32) * 32;
        for (int i = ty; i < 32; i += 8)
            tile[i][tx] = Wfc[(r0 + i) * 1024 + c0 + tx];
        __syncthreads();
        for (int i = ty; i < 32; i += 8)
            wfcT[(long)(c0 + i) * 1024 + r0 + tx] = f2bf(tile[tx][i]);
    } else {
        const int n4 = 1 << 20;
        for (int i = (bid - 4096) * 256 + threadIdx.x; i < n4; i += 1024 * 256) {
            float4 f = ((const float4*)x)[i];
            unsigned a = (unsigned)f2bf(f.x) | ((unsigned)f2bf(f.y) << 16);
            unsigned b = (unsigned)f2bf(f.z) | ((unsigned)f2bf(f.w) << 16);
            ((uint2*)xb)[i] = make_uint2(a, b);
        }
    }
}

// ---------------- per-head V transpose: [1024 n][64 d] -> [64 d][1024 n] ----------------
__global__ void transpose_v(const unsigned short* __restrict__ v,
                            unsigned short* __restrict__ vt) {
    __shared__ unsigned short tile[32][33];
    int bh = blockIdx.z;
    int n0 = blockIdx.x * 32, d0 = blockIdx.y * 32;
    const unsigned short* src = v + (long)bh * 65536;
    unsigned short* dst = vt + (long)bh * 65536;
    for (int i = threadIdx.y; i < 32; i += 8)
        tile[i][threadIdx.x] = src[(n0 + i) * 64 + d0 + threadIdx.x];
    __syncthreads();
    for (int i = threadIdx.y; i < 32; i += 8)
        dst[(d0 + i) * 1024 + n0 + threadIdx.x] = tile[threadIdx.x][i];
}

// ---------------- bf16 GEMM, 128x128 tile, double-buffered global_load_lds ----------------
template <int MODE>
__global__ __launch_bounds__(256) void gemm128(
    const unsigned short* __restrict__ A,    // [M,1024] bf16
    const unsigned short* __restrict__ Bt,   // [N,1024] bf16
    const float* __restrict__ bias,          // [N]
    unsigned short* __restrict__ qb,
    unsigned short* __restrict__ kb,
    unsigned short* __restrict__ vb,
    float* __restrict__ outf)
{
    const int K = 1024;
    __shared__ unsigned short As[2][4096];
    __shared__ unsigned short Bs[2][4096];
    int t = threadIdx.x, lane = t & 63, w = t >> 6;
    int wm = w >> 1, wn = w & 1;
    int lrow = lane >> 4, lcol = lane & 15;

    const int NX  = (MODE == 0) ? 24 : 8;
    const int CPX = (MODE == 0) ? 96 : 32;
    int id = blockIdx.x;
    int idp = (id & 7) * CPX + (id >> 3);    // bijective (grid % 8 == 0)
    int tn0 = (idp % NX) * 128, tm0 = (idp / NX) * 128;

    int seg0 = w * 1024;
    int seg1 = (w + 4) * 1024;
    int off0 = seg0 + lane * 16, off1 = seg1 + lane * 16;
    int r0 = off0 >> 6, cb0 = off0 & 63;
    int r1 = off1 >> 6, cb1 = off1 & 63;

    const char* gA = (const char*)A;
    const char* gB = (const char*)Bt;

    f32x4 acc[4][4] = {};

    auto STAGE = [&](int buf, int kt) {
        long kby = (long)kt * 2;
        gload_lds16(gA + (long)(tm0 + r0) * 2048 + kby + cb0, (char*)&As[buf][0] + seg0);
        gload_lds16(gA + (long)(tm0 + r1) * 2048 + kby + cb1, (char*)&As[buf][0] + seg1);
        gload_lds16(gB + (long)(tn0 + r0) * 2048 + kby + cb0, (char*)&Bs[buf][0] + seg0);
        gload_lds16(gB + (long)(tn0 + r1) * 2048 + kby + cb1, (char*)&Bs[buf][0] + seg1);
    };

    STAGE(0, 0);
    asm volatile("s_waitcnt vmcnt(0)");
    __syncthreads();

    int cur = 0;
    for (int kt = 0; kt < K; kt += 32) {
        if (kt + 32 < K) STAGE(cur ^ 1, kt + 32);

        bf16x8 af[4], bfr[4];
        #pragma unroll
        for (int mi = 0; mi < 4; ++mi)
            af[mi] = ld_frag(&As[cur][0] + (wm * 64 + mi * 16 + lcol) * 32 + lrow * 8);
        #pragma unroll
        for (int ni = 0; ni < 4; ++ni)
            bfr[ni] = ld_frag(&Bs[cur][0] + (wn * 64 + ni * 16 + lcol) * 32 + lrow * 8);
        #pragma unroll
        for (int mi = 0; mi < 4; ++mi)
            #pragma unroll
            for (int ni = 0; ni < 4; ++ni)
                acc[mi][ni] = __builtin_amdgcn_mfma_f32_16x16x32_bf16(af[mi], bfr[ni], acc[mi][ni], 0, 0, 0);

        __syncthreads();
        cur ^= 1;
    }

    #pragma unroll
    for (int mi = 0; mi < 4; ++mi) {
        int gr0 = tm0 + wm * 64 + mi * 16 + lrow * 4;
        #pragma unroll
        for (int ni = 0; ni < 4; ++ni) {
            int gc = tn0 + wn * 64 + ni * 16 + lcol;
            float bv = bias[gc];
            if (MODE == 0) {
                int sec = gc >> 10, ei = gc & 1023;
                unsigned short* dst = sec == 0 ? qb : (sec == 1 ? kb : vb);
                if (sec == 0) {
                    #pragma unroll
                    for (int r = 0; r < 4; ++r)
                        dst[(long)(gr0 + r) * 1024 + ei] = f2bf((acc[mi][ni][r] + bv) * QSCALE);
                } else {
                    #pragma unroll
                    for (int r = 0; r < 4; ++r)
                        dst[(long)(gr0 + r) * 1024 + ei] = f2bf(acc[mi][ni][r] + bv);
                }
            } else {
                #pragma unroll
                for (int r = 0; r < 4; ++r)
                    outf[(long)(gr0 + r) * 1024 + gc] = acc[mi][ni][r] + bv;
            }
        }
    }
}

// ---------------- flash attention: 2-stage pipelined, split-K + pairing + XCD remap ----------------
__global__ __launch_bounds__(256) void attn(
    const unsigned short* __restrict__ qbuf,
    const unsigned short* __restrict__ kbuf,
    const unsigned short* __restrict__ vtbuf,
    unsigned short* __restrict__ obuf)
{
    // smem (17,920 B), phase-aliased:
    //   loop phase : Ps [4][32][40] ushort (10,240 B)
    //   merge phase: accH [4][32][68] f16 (17,408 B) + mS [4][32] f32 (512 B)
    __shared__ char smem[17920] __attribute__((aligned(16)));
    unsigned short (*Ps)[32][40] = (unsigned short (*)[32][40])smem;
    _Float16* accH = (_Float16*)smem;                 // [4][32][68]
    float* mS = (float*)(smem + 17408);               // [4][32]

    int id = blockIdx.x;
    int xcd = id & 7, slot = id >> 3;
    int bh = xcd + 8 * (slot >> 4);
    int j = slot & 15;

    const unsigned short* Q  = qbuf + (long)bh * 65536;
    const unsigned short* Kp = kbuf + (long)bh * 65536;
    const unsigned short* VT = vtbuf + (long)bh * 65536;   // [64 d][1024 n]
    unsigned short* O = obuf + (long)bh * 65536;
    int t = threadIdx.x, lane = t & 63, w = t >> 6;
    int lrow = lane >> 4, lcol = lane & 15;
    const float NEG = -__builtin_inff();

    #pragma unroll
    for (int pass = 0; pass < 2; ++pass) {
        int qt = pass == 0 ? j : 31 - j;
        int qbase = qt * 32;
        int T = qt + 1;

        bf16x8 qf[2][2];
        #pragma unroll
        for (int qg = 0; qg < 2; ++qg)
            #pragma unroll
            for (int kc = 0; kc < 2; ++kc)
                qf[qg][kc] = ld_frag(Q + (long)(qbase + qg * 16 + lcol) * 64 + kc * 32 + lrow * 8);

        f32x4 acc[2][4] = {};
        float m_i[2] = {NEG, NEG};
        float lsum[2][2] = {{0.f, 0.f}, {0.f, 0.f}};

        if (w < T) {
            int kt = w * 32;
            bf16x8 kf[2][2];
            #pragma unroll
            for (int kg = 0; kg < 2; ++kg)
                #pragma unroll
                for (int kc = 0; kc < 2; ++kc)
                    kf[kg][kc] = ld_frag(Kp + (long)(kt + kg * 16 + lcol) * 64 + kc * 32 + lrow * 8);

            // prologue: S for first owned tile
            f32x4 s[2][2] = {};
            #pragma unroll
            for (int kg = 0; kg < 2; ++kg)
                #pragma unroll
                for (int kc = 0; kc < 2; ++kc) {
                    s[0][kg] = __builtin_amdgcn_mfma_f32_16x16x32_bf16(kf[kg][kc], qf[0][kc], s[0][kg], 0, 0, 0);
                    s[1][kg] = __builtin_amdgcn_mfma_f32_16x16x32_bf16(kf[kg][kc], qf[1][kc], s[1][kg], 0, 0, 0);
                }

            for (;;) {
                int ktn = kt + 128;
                bool more = ktn < T * 32;
                // issue next-tile K loads (consumed by QK(t+1) later this iteration)
                if (more) {
                    #pragma unroll
                    for (int kg = 0; kg < 2; ++kg)
                        #pragma unroll
                        for (int kc = 0; kc < 2; ++kc)
                            kf[kg][kc] = ld_frag(Kp + (long)(ktn + kg * 16 + lcol) * 64 + kc * 32 + lrow * 8);
                }
                // issue this tile's V loads
                bf16x8 vf[4];
                #pragma unroll
                for (int dg = 0; dg < 4; ++dg)
                    vf[dg] = ld_frag(VT + (long)(dg * 16 + lcol) * 1024 + kt + lrow * 8);

                // --- softmax on S(t) (computed last iteration / prologue) ---
                bool diag = (kt == qbase);
                if (diag) {
                    #pragma unroll
                    for (int qg = 0; qg < 2; ++qg)
                        #pragma unroll
                        for (int kg = 0; kg < 2; ++kg)
                            #pragma unroll
                            for (int r = 0; r < 4; ++r)
                                if (kg * 16 + lrow * 4 + r > qg * 16 + lcol)
                                    s[qg][kg][r] = NEG;
                }
                float lmax[2];
                #pragma unroll
                for (int qg = 0; qg < 2; ++qg) {
                    float a0 = fmaxf(s[qg][0][0], s[qg][0][1]), a1 = fmaxf(s[qg][0][2], s[qg][0][3]);
                    float a2 = fmaxf(s[qg][1][0], s[qg][1][1]), a3 = fmaxf(s[qg][1][2], s[qg][1][3]);
                    lmax[qg] = fmaxf(fmaxf(a0, a1), fmaxf(a2, a3));
                }
                bool ok = (lmax[0] <= m_i[0] + DEFER_THR) && (lmax[1] <= m_i[1] + DEFER_THR);
                if (!__all(ok)) {
                    #pragma unroll
                    for (int qg = 0; qg < 2; ++qg) {
                        float mx = fmaxf(lmax[qg], __shfl_xor(lmax[qg], 16));
                        mx = fmaxf(mx, __shfl_xor(mx, 32));
                        float mnew = fmaxf(m_i[qg], mx);
                        float alpha = exp2f(m_i[qg] - mnew);
                        m_i[qg] = mnew;
                        lsum[qg][0] *= alpha;
                        lsum[qg][1] *= alpha;
                        #pragma unroll
                        for (int dg = 0; dg < 4; ++dg)
                            #pragma unroll
                            for (int r = 0; r < 4; ++r)
                                acc[qg][dg][r] *= alpha;
                    }
                }
                #pragma unroll
                for (int qg = 0; qg < 2; ++qg) {
                    float p[8];
                    #pragma unroll
                    for (int kg = 0; kg < 2; ++kg)
                        #pragma unroll
                        for (int r = 0; r < 4; ++r)
                            p[kg * 4 + r] = exp2f(s[qg][kg][r] - m_i[qg]);
                    lsum[qg][0] += (p[0] + p[1]) + (p[2] + p[3]);
                    lsum[qg][1] += (p[4] + p[5]) + (p[6] + p[7]);
                    unsigned u0 = cvtpk_bf16(p[0], p[1]);
                    unsigned u1 = cvtpk_bf16(p[2], p[3]);
                    unsigned u2 = cvtpk_bf16(p[4], p[5]);
                    unsigned u3 = cvtpk_bf16(p[6], p[7]);
                    *(uint2*)&Ps[w][qg * 16 + lcol][lrow * 4]      = make_uint2(u0, u1);
                    *(uint2*)&Ps[w][qg * 16 + lcol][16 + lrow * 4] = make_uint2(u2, u3);
                }

                bf16x8 pb[2];
                pb[0] = ld_frag(&Ps[w][lcol][lrow * 8]);
                pb[1] = ld_frag(&Ps[w][16 + lcol][lrow * 8]);

                __builtin_amdgcn_s_setprio(1);
                // --- QK(t+1) first: fills MFMA pipe, latency hides under PV + next softmax ---
                if (more) {
                    #pragma unroll
                    for (int qg = 0; qg < 2; ++qg)
                        #pragma unroll
                        for (int kg = 0; kg < 2; ++kg)
                            s[qg][kg] = (f32x4){0.f, 0.f, 0.f, 0.f};
                    #pragma unroll
                    for (int kg = 0; kg < 2; ++kg)
                        #pragma unroll
                        for (int kc = 0; kc < 2; ++kc) {
                            s[0][kg] = __builtin_amdgcn_mfma_f32_16x16x32_bf16(kf[kg][kc], qf[0][kc], s[0][kg], 0, 0, 0);
                            s[1][kg] = __builtin_amdgcn_mfma_f32_16x16x32_bf16(kf[kg][kc], qf[1][kc], s[1][kg], 0, 0, 0);
                        }
                }
                // --- PV(t) ---
                #pragma unroll
                for (int dg = 0; dg < 4; ++dg) {
                    acc[0][dg] = __builtin_amdgcn_mfma_f32_16x16x32_bf16(vf[dg], pb[0], acc[0][dg], 0, 0, 0);
                    acc[1][dg] = __builtin_amdgcn_mfma_f32_16x16x32_bf16(vf[dg], pb[1], acc[1][dg], 0, 0, 0);
                }
                __builtin_amdgcn_s_setprio(0);

                if (!more) break;
                kt = ktn;
            }
        }

        // --- merge 4 wave-partials through LDS (f16 l-normalized) ---
        __syncthreads();
        #pragma unroll
        for (int qg = 0; qg < 2; ++qg) {
            int q = qg * 16 + lcol;
            float lr = lsum[qg][0] + lsum[qg][1];
            lr += __shfl_xor(lr, 16);
            lr += __shfl_xor(lr, 32);
            float mprime, inv;
            if (lr > 0.f) { mprime = m_i[qg] + log2f(lr); inv = 1.f / lr; }
            else          { mprime = NEG; inv = 0.f; }
            if (lrow == 0) mS[w * 32 + q] = mprime;
            #pragma unroll
            for (int dg = 0; dg < 4; ++dg) {
                _Float16 a0 = (_Float16)(acc[qg][dg][0] * inv);
                _Float16 a1 = (_Float16)(acc[qg][dg][1] * inv);
                _Float16 a2 = (_Float16)(acc[qg][dg][2] * inv);
                _Float16 a3 = (_Float16)(acc[qg][dg][3] * inv);
                _Float16* dst = &accH[(w * 32 + q) * 68 + dg * 16 + lrow * 4];
                dst[0] = a0; dst[1] = a1; dst[2] = a2; dst[3] = a3;
            }
        }
        __syncthreads();

        {
            int qq = t >> 3, d0 = (t & 7) * 8;
            float m0 = mS[qq], m1 = mS[32 + qq], m2 = mS[64 + qq], m3 = mS[96 + qq];
            float M = fmaxf(fmaxf(m0, m1), fmaxf(m2, m3));
            float e0 = exp2f(m0 - M), e1 = exp2f(m1 - M), e2 = exp2f(m2 - M), e3 = exp2f(m3 - M);
            float inv = 1.f / (e0 + e1 + e2 + e3);
            const _Float16* a0 = &accH[qq * 68 + d0];
            const _Float16* a1 = &accH[(32 + qq) * 68 + d0];
            const _Float16* a2 = &accH[(64 + qq) * 68 + d0];
            const _Float16* a3 = &accH[(96 + qq) * 68 + d0];
            unsigned short h[8];
            #pragma unroll
            for (int jj = 0; jj < 8; ++jj)
                h[jj] = f2bf((e0 * (float)a0[jj] + e1 * (float)a1[jj] +
                              e2 * (float)a2[jj] + e3 * (float)a3[jj]) * inv);
            uint4 pk;
            pk.x = (unsigned)h[0] | ((unsigned)h[1] << 16);
            pk.y = (unsigned)h[2] | ((unsigned)h[3] << 16);
            pk.z = (unsigned)h[4] | ((unsigned)h[5] << 16);
            pk.w = (unsigned)h[6] | ((unsigned)h[7] << 16);
            *(uint4*)&O[(long)(qbase + qq) * 64 + d0] = pk;
        }
        __syncthreads();
    }
}

extern "C" void kernel_launch(void* const* d_in, const int* in_sizes, int n_in,
                              void* d_out, int out_size, void* d_ws, size_t ws_size,
                              hipStream_t stream) {
    const float* x    = (const float*)d_in[0];
    const float* Wqkv = (const float*)d_in[1];
    const float* bqkv = (const float*)d_in[2];
    const float* Wfc  = (const float*)d_in[3];
    const float* bfc  = (const float*)d_in[4];
    float* out = (float*)d_out;

    unsigned short* ws    = (unsigned short*)d_ws;
    unsigned short* xb    = ws;                    // 4M elems; dead after gemm<0>
    unsigned short* wqkvT = xb + (4u << 20);       // 3M
    unsigned short* wfcT  = wqkvT + (3u << 20);    // 1M
    unsigned short* qb    = wfcT + (1u << 20);     // 4M
    unsigned short* kb    = qb + (4u << 20);       // 4M
    unsigned short* vb    = kb + (4u << 20);       // 4M; dead after transpose_v
    unsigned short* vbT   = xb;                    // reuse xb
    unsigned short* ob    = vb;                    // reuse vb
    // total ws: 40 MB

    prep<<<dim3(5120), dim3(256), 0, stream>>>(x, xb, Wqkv, wqkvT, Wfc, wfcT);
    gemm128<0><<<dim3(768), dim3(256), 0, stream>>>(xb, wqkvT, bqkv, qb, kb, vb, nullptr);
    transpose_v<<<dim3(32, 2, 64), dim3(32, 8), 0, stream>>>(vb, vbT);
    attn<<<dim3(1024), dim3(256), 0, stream>>>(qb, kb, vbT, ob);
    gemm128<1><<<dim3(256), dim3(256), 0, stream>>>(ob, wfcT, bfc, nullptr, nullptr, nullptr, out);
}